// Round 2
// baseline (248.645 us; speedup 1.0000x reference)
//
#include <hip/hip_runtime.h>
#include <hip/hip_bf16.h>
#include <stdint.h>

typedef __bf16 bf16_t;
typedef float floatx4 __attribute__((ext_vector_type(4)));
typedef __bf16 bf16x8 __attribute__((ext_vector_type(8)));
typedef __bf16 bf16x4 __attribute__((ext_vector_type(4)));

// scale = DH^-0.5 * log2(e), folded into Q at GEMM epilogue so softmax uses raw exp2
#define QSCALE 0.1803368801111204f

// -------------------- async global->LDS (16B) --------------------
__device__ __forceinline__ void gl2lds16(const bf16_t* g, bf16_t* l) {
    __builtin_amdgcn_global_load_lds(
        (const __attribute__((address_space(1))) unsigned int*)g,
        (__attribute__((address_space(3))) unsigned int*)l,
        16, 0, 0);
}

// -------------------- fp32 -> bf16 convert --------------------
__global__ __launch_bounds__(256) void convert_kernel(const float* __restrict__ in,
                                                      bf16_t* __restrict__ out, int n4) {
    int i = blockIdx.x * 256 + threadIdx.x;
    if (i < n4) {
        float4 v = ((const float4*)in)[i];
        bf16x4 o;
        o.x = (bf16_t)v.x; o.y = (bf16_t)v.y; o.z = (bf16_t)v.z; o.w = (bf16_t)v.w;
        ((bf16x4*)out)[i] = o;
    }
}

// -------------------- QKV projection GEMM (gemm_bt) --------------------
__global__ __launch_bounds__(256) void qkv_gemm(const bf16_t* __restrict__ X,   // [8192][512]
                                                const bf16_t* __restrict__ W,   // [1536][512]
                                                bf16_t* __restrict__ Q,         // [32][2048][64] (pre-scaled)
                                                bf16_t* __restrict__ K,         // [32][2048][64]
                                                bf16_t* __restrict__ Vt)        // [32][64][2048]
{
    __shared__ bf16_t As[128 * 64];
    __shared__ bf16_t Bs[128 * 64];

    const int tid  = threadIdx.x;
    const int wave = tid >> 6;
    const int lane = tid & 63;
    const int quad = lane >> 4;
    const int lrow = lane & 15;
    const int bm0 = blockIdx.x * 128;
    const int bn0 = blockIdx.y * 128;
    const int mw = (wave >> 1) * 64;
    const int nw = (wave & 1) * 64;
    const int wbase = tid & 192;   // wave*64, wave-uniform

    floatx4 acc[4][4];
#pragma unroll
    for (int i = 0; i < 4; i++)
#pragma unroll
        for (int j = 0; j < 4; j++) acc[i][j] = (floatx4)0.0f;

#pragma unroll 1
    for (int kb = 0; kb < 8; ++kb) {
        const int k0 = kb * 64;
        __syncthreads();
#pragma unroll
        for (int r = 0; r < 4; ++r) {
            int c = r * 256 + tid;
            int row = c >> 3, kc = c & 7;
            gl2lds16(X + (size_t)(bm0 + row) * 512 + k0 + kc * 8,
                     As + (size_t)(r * 256 + wbase) * 8);
        }
#pragma unroll
        for (int r = 0; r < 4; ++r) {
            int c = r * 256 + tid;
            int row = c >> 3, kc = c & 7;
            gl2lds16(W + (size_t)(bn0 + row) * 512 + k0 + kc * 8,
                     Bs + (size_t)(r * 256 + wbase) * 8);
        }
        __syncthreads();
#pragma unroll
        for (int ks = 0; ks < 2; ++ks) {
            bf16x8 af[4], bfr[4];
#pragma unroll
            for (int mi = 0; mi < 4; mi++)
                af[mi] = *(const bf16x8*)(As + (mw + mi * 16 + lrow) * 64 + ks * 32 + quad * 8);
#pragma unroll
            for (int ni = 0; ni < 4; ni++)
                bfr[ni] = *(const bf16x8*)(Bs + (nw + ni * 16 + lrow) * 64 + ks * 32 + quad * 8);
#pragma unroll
            for (int mi = 0; mi < 4; mi++)
#pragma unroll
                for (int ni = 0; ni < 4; ni++)
                    acc[mi][ni] = __builtin_amdgcn_mfma_f32_16x16x32_bf16(af[mi], bfr[ni], acc[mi][ni], 0, 0, 0);
        }
    }

    // epilogue: C/D layout col=lane&15, row=quad*4+reg  [verified m89]
#pragma unroll
    for (int mi = 0; mi < 4; mi++) {
        int mbase = bm0 + mw + mi * 16 + quad * 4;
        int b = mbase >> 11, n = mbase & 2047;   // r=0..3 never crosses a batch boundary (mbase%4==0)
#pragma unroll
        for (int ni = 0; ni < 4; ni++) {
            int o = bn0 + nw + ni * 16 + lrow;
            int s  = o >> 9;
            int h  = (o >> 6) & 7;
            int dh = o & 63;
            int bh = b * 8 + h;
            if (s == 2) {
                bf16x4 pv;
#pragma unroll
                for (int r = 0; r < 4; r++) pv[r] = (bf16_t)acc[mi][ni][r];
                *(bf16x4*)(Vt + ((size_t)bh * 64 + dh) * 2048 + n) = pv;   // 8B packed, n%4==0
            } else if (s == 0) {
#pragma unroll
                for (int r = 0; r < 4; r++)
                    Q[((size_t)bh * 2048 + n + r) * 64 + dh] = (bf16_t)(acc[mi][ni][r] * QSCALE);
            } else {
#pragma unroll
                for (int r = 0; r < 4; r++)
                    K[((size_t)bh * 2048 + n + r) * 64 + dh] = (bf16_t)acc[mi][ni][r];
            }
        }
    }
}

// -------------------- flash attention (no-max softmax: scores bounded ~|1.6|) --------------------
#define KP 72   // pitch: 16B-aligned rows; K/V/P b128 reads provably at 8-dword/bank minimum

__global__ __launch_bounds__(256) void flash_attn(const bf16_t* __restrict__ Q,   // [32][2048][64], pre-scaled by 0.125*log2e
                                                  const bf16_t* __restrict__ K,   // [32][2048][64]
                                                  const bf16_t* __restrict__ Vt,  // [32][64][2048]
                                                  float* __restrict__ Out)        // [4][2048][512]
{
    __shared__ bf16_t Ks[64 * KP];
    __shared__ bf16_t Vs[64 * KP];
    __shared__ bf16_t Ps[4][16 * KP];

    const int tid  = threadIdx.x;
    const int wave = tid >> 6;
    const int lane = tid & 63;
    const int quad = lane >> 4;
    const int c    = lane & 15;
    const int qt = blockIdx.x;
    const int bh = blockIdx.y;
    const int b = bh >> 3, h = bh & 7;

    // Q fragments (A-operand: m=lane&15, k=quad*8+j), shifted-query source row
    int qg  = qt * 64 + wave * 16 + c;
    int src = (qg == 0) ? 0 : qg - 1;
    const bf16_t* qbase = Q + ((size_t)bh * 2048 + src) * 64;
    bf16x8 qf0 = *(const bf16x8*)(qbase + quad * 8);
    bf16x8 qf1 = *(const bf16x8*)(qbase + 32 + quad * 8);

    floatx4 o[4];
#pragma unroll
    for (int i = 0; i < 4; i++) o[i] = (floatx4)0.0f;
    float lacc[4] = {0.f, 0.f, 0.f, 0.f};

    const int srow = tid >> 3;   // 0..31
    const int skc  = tid & 7;
    const bf16_t* kb = K + ((size_t)bh * 2048) * 64;
    const bf16_t* vb = Vt + ((size_t)bh * 64) * 2048;
    bf16_t* pw = Ps[wave];

    // register prefetch of tile 0
    uint4 kreg[2], vreg[2];
#pragma unroll
    for (int rr = 0; rr < 2; ++rr) {
        int row = srow + rr * 32;
        kreg[rr] = *(const uint4*)(kb + (size_t)row * 64 + skc * 8);
        vreg[rr] = *(const uint4*)(vb + (size_t)row * 2048 + skc * 8);
    }

#pragma unroll 1
    for (int kt = 0; kt < 32; ++kt) {
        __syncthreads();   // prior tile's LDS reads done
#pragma unroll
        for (int rr = 0; rr < 2; ++rr) {
            int row = srow + rr * 32;
            *(uint4*)(Ks + row * KP + skc * 8) = kreg[rr];
            *(uint4*)(Vs + row * KP + skc * 8) = vreg[rr];
        }
        if (kt < 31) {   // prefetch next tile; latency hidden behind compute phase
#pragma unroll
            for (int rr = 0; rr < 2; ++rr) {
                int row = srow + rr * 32;
                kreg[rr] = *(const uint4*)(kb + ((size_t)((kt + 1) * 64 + row)) * 64 + skc * 8);
                vreg[rr] = *(const uint4*)(vb + (size_t)row * 2048 + (kt + 1) * 64 + skc * 8);
            }
        }
        __syncthreads();

        // S = Qc * K^T  (per wave: 16 q x 64 keys); log2e pre-folded
        floatx4 s[4];
#pragma unroll
        for (int sub = 0; sub < 4; ++sub) {
            bf16x8 kf0 = *(const bf16x8*)(Ks + (sub * 16 + c) * KP + quad * 8);
            bf16x8 kf1 = *(const bf16x8*)(Ks + (sub * 16 + c) * KP + 32 + quad * 8);
            floatx4 t = (floatx4)0.0f;
            t = __builtin_amdgcn_mfma_f32_16x16x32_bf16(qf0, kf0, t, 0, 0, 0);
            t = __builtin_amdgcn_mfma_f32_16x16x32_bf16(qf1, kf1, t, 0, 0, 0);
            s[sub] = t;
        }

        // P = exp2(S); in-lane partial row sums only (cross-lane reduce deferred to epilogue)
#pragma unroll
        for (int sub = 0; sub < 4; ++sub)
#pragma unroll
            for (int r = 0; r < 4; r++) {
                float p = __builtin_amdgcn_exp2f(s[sub][r]);
                lacc[r] += p;
                pw[(quad * 4 + r) * KP + sub * 16 + c] = (bf16_t)p;
            }
        // NO barrier: Ps is per-wave; in-wave DS ordering (lgkmcnt) suffices

        // O += P * V
#pragma unroll
        for (int ks = 0; ks < 2; ++ks) {
            bf16x8 pf = *(const bf16x8*)(pw + c * KP + ks * 32 + quad * 8);
#pragma unroll
            for (int sub = 0; sub < 4; ++sub) {
                bf16x8 vf = *(const bf16x8*)(Vs + (sub * 16 + c) * KP + ks * 32 + quad * 8);
                o[sub] = __builtin_amdgcn_mfma_f32_16x16x32_bf16(pf, vf, o[sub], 0, 0, 0);
            }
        }
    }

    // final cross-lane row-sum reduction (rows at quad*4+r; cols spread over 16 c-lanes)
#pragma unroll
    for (int r = 0; r < 4; r++)
#pragma unroll
        for (int d = 1; d < 16; d <<= 1)
            lacc[r] += __shfl_xor(lacc[r], d, 64);

    // epilogue: out[b][n][h*64 + d] = o / l
    int n0 = qt * 64 + wave * 16 + quad * 4;
    float* ob = Out + (size_t)b * 2048 * 512 + (size_t)h * 64;
#pragma unroll
    for (int r = 0; r < 4; r++) {
        float inv = 1.0f / lacc[r];
        float* orow = ob + (size_t)(n0 + r) * 512;
#pragma unroll
        for (int sub = 0; sub < 4; ++sub)
            orow[sub * 16 + c] = o[sub][r] * inv;
    }
}

// -------------------- launch --------------------
extern "C" void kernel_launch(void* const* d_in, const int* in_sizes, int n_in,
                              void* d_out, int out_size, void* d_ws, size_t ws_size,
                              hipStream_t stream) {
    const float* x = (const float*)d_in[0];   // [4,2048,512]
    const float* w = (const float*)d_in[1];   // [1536,512]
    float* out = (float*)d_out;               // [4,2048,512]

    char* ws = (char*)d_ws;
    bf16_t* xb = (bf16_t*)(ws);                       //  8 MB
    bf16_t* wb = (bf16_t*)(ws + 8388608);             //  1.5 MB
    bf16_t* q  = (bf16_t*)(ws + 9961472);             //  8 MB
    bf16_t* k  = (bf16_t*)(ws + 18350080);            //  8 MB
    bf16_t* vt = (bf16_t*)(ws + 26738688);            //  8 MB (end 33.5 MB)

    convert_kernel<<<4096, 256, 0, stream>>>(x, xb, 1048576);
    convert_kernel<<<768, 256, 0, stream>>>(w, wb, 196608);
    qkv_gemm<<<dim3(64, 12), 256, 0, stream>>>(xb, wb, q, k, vt);
    flash_attn<<<dim3(32, 32), 256, 0, stream>>>(q, k, vt, out);
}

// Round 3
// 178.287 us; speedup vs baseline: 1.3946x; 1.3946x over previous
//
#include <hip/hip_runtime.h>
#include <hip/hip_bf16.h>
#include <stdint.h>

typedef __bf16 bf16_t;
typedef float floatx4 __attribute__((ext_vector_type(4)));
typedef __bf16 bf16x8 __attribute__((ext_vector_type(8)));
typedef __bf16 bf16x4 __attribute__((ext_vector_type(4)));

// scale = DH^-0.5 * log2(e), folded into Q at GEMM epilogue so softmax uses raw exp2
#define QSCALE 0.1803368801111204f

// -------------------- async global->LDS (16B) --------------------
__device__ __forceinline__ void gl2lds16(const bf16_t* g, bf16_t* l) {
    __builtin_amdgcn_global_load_lds(
        (const __attribute__((address_space(1))) unsigned int*)g,
        (__attribute__((address_space(3))) unsigned int*)l,
        16, 0, 0);
}

// -------------------- fp32 -> bf16 convert (x and W fused) --------------------
__global__ __launch_bounds__(256) void convert_kernel(const float* __restrict__ x,
                                                      bf16_t* __restrict__ xb,
                                                      const float* __restrict__ w,
                                                      bf16_t* __restrict__ wb,
                                                      int nx4) {   // x chunks; W chunks follow
    int i = blockIdx.x * 256 + threadIdx.x;
    const float* in; bf16_t* out; int j;
    if (i < nx4) { in = x; out = xb; j = i; }
    else         { in = w; out = wb; j = i - nx4; }
    float4 v = ((const float4*)in)[j];
    bf16x4 o;
    o.x = (bf16_t)v.x; o.y = (bf16_t)v.y; o.z = (bf16_t)v.z; o.w = (bf16_t)v.w;
    ((bf16x4*)out)[j] = o;
}

// -------------------- QKV projection GEMM (gemm_bt) --------------------
__global__ __launch_bounds__(256) void qkv_gemm(const bf16_t* __restrict__ X,   // [8192][512]
                                                const bf16_t* __restrict__ W,   // [1536][512]
                                                bf16_t* __restrict__ Q,         // [32][2048][64] (pre-scaled)
                                                bf16_t* __restrict__ K,         // [32][2048][64]
                                                bf16_t* __restrict__ Vt)        // [32][64][2048]
{
    __shared__ bf16_t As[128 * 64];
    __shared__ bf16_t Bs[128 * 64];

    const int tid  = threadIdx.x;
    const int wave = tid >> 6;
    const int lane = tid & 63;
    const int quad = lane >> 4;
    const int lrow = lane & 15;
    const int bm0 = blockIdx.x * 128;
    const int bn0 = blockIdx.y * 128;
    const int mw = (wave >> 1) * 64;
    const int nw = (wave & 1) * 64;
    const int wbase = tid & 192;   // wave*64, wave-uniform

    floatx4 acc[4][4];
#pragma unroll
    for (int i = 0; i < 4; i++)
#pragma unroll
        for (int j = 0; j < 4; j++) acc[i][j] = (floatx4)0.0f;

#pragma unroll 1
    for (int kb = 0; kb < 8; ++kb) {
        const int k0 = kb * 64;
        __syncthreads();
#pragma unroll
        for (int r = 0; r < 4; ++r) {
            int c = r * 256 + tid;
            int row = c >> 3, kc = c & 7;
            gl2lds16(X + (size_t)(bm0 + row) * 512 + k0 + kc * 8,
                     As + (size_t)(r * 256 + wbase) * 8);
        }
#pragma unroll
        for (int r = 0; r < 4; ++r) {
            int c = r * 256 + tid;
            int row = c >> 3, kc = c & 7;
            gl2lds16(W + (size_t)(bn0 + row) * 512 + k0 + kc * 8,
                     Bs + (size_t)(r * 256 + wbase) * 8);
        }
        __syncthreads();
#pragma unroll
        for (int ks = 0; ks < 2; ++ks) {
            bf16x8 af[4], bfr[4];
#pragma unroll
            for (int mi = 0; mi < 4; mi++)
                af[mi] = *(const bf16x8*)(As + (mw + mi * 16 + lrow) * 64 + ks * 32 + quad * 8);
#pragma unroll
            for (int ni = 0; ni < 4; ni++)
                bfr[ni] = *(const bf16x8*)(Bs + (nw + ni * 16 + lrow) * 64 + ks * 32 + quad * 8);
#pragma unroll
            for (int mi = 0; mi < 4; mi++)
#pragma unroll
                for (int ni = 0; ni < 4; ni++)
                    acc[mi][ni] = __builtin_amdgcn_mfma_f32_16x16x32_bf16(af[mi], bfr[ni], acc[mi][ni], 0, 0, 0);
        }
    }

    // epilogue: C/D layout col=lane&15, row=quad*4+reg  [verified m89]
#pragma unroll
    for (int mi = 0; mi < 4; mi++) {
        int mbase = bm0 + mw + mi * 16 + quad * 4;
        int b = mbase >> 11, n = mbase & 2047;   // r never crosses batch boundary (mbase%4==0)
#pragma unroll
        for (int ni = 0; ni < 4; ni++) {
            int o = bn0 + nw + ni * 16 + lrow;
            int s  = o >> 9;
            int h  = (o >> 6) & 7;
            int dh = o & 63;
            int bh = b * 8 + h;
            if (s == 2) {
                bf16x4 pv;
#pragma unroll
                for (int r = 0; r < 4; r++) pv[r] = (bf16_t)acc[mi][ni][r];
                *(bf16x4*)(Vt + ((size_t)bh * 64 + dh) * 2048 + n) = pv;   // 8B packed
            } else if (s == 0) {
#pragma unroll
                for (int r = 0; r < 4; r++)
                    Q[((size_t)bh * 2048 + n + r) * 64 + dh] = (bf16_t)(acc[mi][ni][r] * QSCALE);
            } else {
#pragma unroll
                for (int r = 0; r < 4; r++)
                    K[((size_t)bh * 2048 + n + r) * 64 + dh] = (bf16_t)acc[mi][ni][r];
            }
        }
    }
}

// -------------------- flash attention (no-max softmax: scores bounded ~|1.6|) --------------------
// R1 staging structure (load->LDS same iteration, NO long-live-range register
// prefetch: R2 showed the allocator spills it -> 210 MB scratch traffic).
#define KP 72   // pitch: 16B-aligned rows; K/V/P b128 reads at 2-way aliasing (free, m136)

__global__ __launch_bounds__(256) void flash_attn(const bf16_t* __restrict__ Q,   // [32][2048][64], pre-scaled by 0.125*log2e
                                                  const bf16_t* __restrict__ K,   // [32][2048][64]
                                                  const bf16_t* __restrict__ Vt,  // [32][64][2048]
                                                  float* __restrict__ Out)        // [4][2048][512]
{
    __shared__ bf16_t Ks[64 * KP];
    __shared__ bf16_t Vs[64 * KP];
    __shared__ bf16_t Ps[4][16 * KP];

    const int tid  = threadIdx.x;
    const int wave = tid >> 6;
    const int lane = tid & 63;
    const int quad = lane >> 4;
    const int c    = lane & 15;
    const int qt = blockIdx.x;
    const int bh = blockIdx.y;
    const int b = bh >> 3, h = bh & 7;

    // Q fragments (A-operand: m=lane&15, k=quad*8+j), shifted-query source row
    int qg  = qt * 64 + wave * 16 + c;
    int src = (qg == 0) ? 0 : qg - 1;
    const bf16_t* qbase = Q + ((size_t)bh * 2048 + src) * 64;
    bf16x8 qf0 = *(const bf16x8*)(qbase + quad * 8);
    bf16x8 qf1 = *(const bf16x8*)(qbase + 32 + quad * 8);

    floatx4 o[4];
#pragma unroll
    for (int i = 0; i < 4; i++) o[i] = (floatx4)0.0f;
    float lacc[4] = {0.f, 0.f, 0.f, 0.f};

    const int srow = tid >> 3;   // 0..31
    const int skc  = tid & 7;
    const bf16_t* kb = K + ((size_t)bh * 2048) * 64;
    const bf16_t* vb = Vt + ((size_t)bh * 64) * 2048;
    bf16_t* pw = Ps[wave];

#pragma unroll 1
    for (int kt = 0; kt < 32; ++kt) {
        __syncthreads();
        // stage K tile [64][64] and V^T tile [64 d][64 key] into padded LDS
#pragma unroll
        for (int rr = 0; rr < 2; ++rr) {
            int row = srow + rr * 32;
            *(uint4*)(Ks + row * KP + skc * 8) =
                *(const uint4*)(kb + ((size_t)(kt * 64 + row)) * 64 + skc * 8);
            *(uint4*)(Vs + row * KP + skc * 8) =
                *(const uint4*)(vb + (size_t)row * 2048 + kt * 64 + skc * 8);
        }
        __syncthreads();

        // S = Qc * K^T  (per wave: 16 q x 64 keys); log2e pre-folded
        floatx4 s[4];
#pragma unroll
        for (int sub = 0; sub < 4; ++sub) {
            bf16x8 kf0 = *(const bf16x8*)(Ks + (sub * 16 + c) * KP + quad * 8);
            bf16x8 kf1 = *(const bf16x8*)(Ks + (sub * 16 + c) * KP + 32 + quad * 8);
            floatx4 t = (floatx4)0.0f;
            t = __builtin_amdgcn_mfma_f32_16x16x32_bf16(qf0, kf0, t, 0, 0, 0);
            t = __builtin_amdgcn_mfma_f32_16x16x32_bf16(qf1, kf1, t, 0, 0, 0);
            s[sub] = t;
        }

        // P = exp2(S); in-lane partial row sums (cross-lane reduce deferred to epilogue)
#pragma unroll
        for (int sub = 0; sub < 4; ++sub)
#pragma unroll
            for (int r = 0; r < 4; r++) {
                float p = __builtin_amdgcn_exp2f(s[sub][r]);
                lacc[r] += p;
                pw[(quad * 4 + r) * KP + sub * 16 + c] = (bf16_t)p;
            }
        // NO barrier: Ps is per-wave; in-wave DS ordering (lgkmcnt) suffices

        // O += P * V
#pragma unroll
        for (int ks = 0; ks < 2; ++ks) {
            bf16x8 pf = *(const bf16x8*)(pw + c * KP + ks * 32 + quad * 8);
#pragma unroll
            for (int sub = 0; sub < 4; ++sub) {
                bf16x8 vf = *(const bf16x8*)(Vs + (sub * 16 + c) * KP + ks * 32 + quad * 8);
                o[sub] = __builtin_amdgcn_mfma_f32_16x16x32_bf16(pf, vf, o[sub], 0, 0, 0);
            }
        }
    }

    // final cross-lane row-sum reduction (16-lane groups: masks 1,2,4,8 keep quad bits)
#pragma unroll
    for (int r = 0; r < 4; r++)
#pragma unroll
        for (int d = 1; d < 16; d <<= 1)
            lacc[r] += __shfl_xor(lacc[r], d, 64);

    // epilogue: out[b][n][h*64 + d] = o / l
    int n0 = qt * 64 + wave * 16 + quad * 4;
    float* ob = Out + (size_t)b * 2048 * 512 + (size_t)h * 64;
#pragma unroll
    for (int r = 0; r < 4; r++) {
        float inv = 1.0f / lacc[r];
        float* orow = ob + (size_t)(n0 + r) * 512;
#pragma unroll
        for (int sub = 0; sub < 4; ++sub)
            orow[sub * 16 + c] = o[sub][r] * inv;
    }
}

// -------------------- launch --------------------
extern "C" void kernel_launch(void* const* d_in, const int* in_sizes, int n_in,
                              void* d_out, int out_size, void* d_ws, size_t ws_size,
                              hipStream_t stream) {
    const float* x = (const float*)d_in[0];   // [4,2048,512]
    const float* w = (const float*)d_in[1];   // [1536,512]
    float* out = (float*)d_out;               // [4,2048,512]

    char* ws = (char*)d_ws;
    bf16_t* xb = (bf16_t*)(ws);                       //  8 MB
    bf16_t* wb = (bf16_t*)(ws + 8388608);             //  1.5 MB
    bf16_t* q  = (bf16_t*)(ws + 9961472);             //  8 MB
    bf16_t* k  = (bf16_t*)(ws + 18350080);            //  8 MB
    bf16_t* vt = (bf16_t*)(ws + 26738688);            //  8 MB (end 33.5 MB)

    // 1,048,576 x-chunks + 196,608 W-chunks = 1,245,184 = 4864 blocks * 256
    convert_kernel<<<4864, 256, 0, stream>>>(x, xb, w, wb, 1048576);
    qkv_gemm<<<dim3(64, 12), 256, 0, stream>>>(xb, wb, q, k, vt);
    flash_attn<<<dim3(32, 32), 256, 0, stream>>>(q, k, vt, out);
}

// Round 4
// 160.295 us; speedup vs baseline: 1.5512x; 1.1122x over previous
//
#include <hip/hip_runtime.h>
#include <hip/hip_bf16.h>
#include <stdint.h>

typedef __bf16 bf16_t;
typedef float floatx4 __attribute__((ext_vector_type(4)));
typedef __bf16 bf16x8 __attribute__((ext_vector_type(8)));
typedef __bf16 bf16x4 __attribute__((ext_vector_type(4)));

// scale = DH^-0.5 * log2(e), folded into Q at GEMM epilogue so softmax uses raw exp2
#define QSCALE 0.1803368801111204f

// -------------------- async global->LDS (16B) --------------------
__device__ __forceinline__ void gl2lds16(const bf16_t* g, bf16_t* l) {
    __builtin_amdgcn_global_load_lds(
        (const __attribute__((address_space(1))) unsigned int*)g,
        (__attribute__((address_space(3))) unsigned int*)l,
        16, 0, 0);
}

// -------------------- fp32 -> bf16 convert (x and W fused) --------------------
__global__ __launch_bounds__(256) void convert_kernel(const float* __restrict__ x,
                                                      bf16_t* __restrict__ xb,
                                                      const float* __restrict__ w,
                                                      bf16_t* __restrict__ wb,
                                                      int nx4) {   // x chunks; W chunks follow
    int i = blockIdx.x * 256 + threadIdx.x;
    const float* in; bf16_t* out; int j;
    if (i < nx4) { in = x; out = xb; j = i; }
    else         { in = w; out = wb; j = i - nx4; }
    float4 v = ((const float4*)in)[j];
    bf16x4 o;
    o.x = (bf16_t)v.x; o.y = (bf16_t)v.y; o.z = (bf16_t)v.z; o.w = (bf16_t)v.w;
    ((bf16x4*)out)[j] = o;
}

// -------------------- QKV projection GEMM (gemm_bt) --------------------
__global__ __launch_bounds__(256) void qkv_gemm(const bf16_t* __restrict__ X,   // [8192][512]
                                                const bf16_t* __restrict__ W,   // [1536][512]
                                                bf16_t* __restrict__ Q,         // [32][2048][64] (pre-scaled)
                                                bf16_t* __restrict__ K,         // [32][2048][64]
                                                bf16_t* __restrict__ Vt)        // [32][64][2048]
{
    __shared__ bf16_t As[128 * 64];
    __shared__ bf16_t Bs[128 * 64];

    const int tid  = threadIdx.x;
    const int wave = tid >> 6;
    const int lane = tid & 63;
    const int quad = lane >> 4;
    const int lrow = lane & 15;
    const int bm0 = blockIdx.x * 128;
    const int bn0 = blockIdx.y * 128;
    const int mw = (wave >> 1) * 64;
    const int nw = (wave & 1) * 64;
    const int wbase = tid & 192;   // wave*64, wave-uniform

    floatx4 acc[4][4];
#pragma unroll
    for (int i = 0; i < 4; i++)
#pragma unroll
        for (int j = 0; j < 4; j++) acc[i][j] = (floatx4)0.0f;

#pragma unroll 1
    for (int kb = 0; kb < 8; ++kb) {
        const int k0 = kb * 64;
        __syncthreads();
#pragma unroll
        for (int r = 0; r < 4; ++r) {
            int c = r * 256 + tid;
            int row = c >> 3, kc = c & 7;
            gl2lds16(X + (size_t)(bm0 + row) * 512 + k0 + kc * 8,
                     As + (size_t)(r * 256 + wbase) * 8);
        }
#pragma unroll
        for (int r = 0; r < 4; ++r) {
            int c = r * 256 + tid;
            int row = c >> 3, kc = c & 7;
            gl2lds16(W + (size_t)(bn0 + row) * 512 + k0 + kc * 8,
                     Bs + (size_t)(r * 256 + wbase) * 8);
        }
        __syncthreads();
#pragma unroll
        for (int ks = 0; ks < 2; ++ks) {
            bf16x8 af[4], bfr[4];
#pragma unroll
            for (int mi = 0; mi < 4; mi++)
                af[mi] = *(const bf16x8*)(As + (mw + mi * 16 + lrow) * 64 + ks * 32 + quad * 8);
#pragma unroll
            for (int ni = 0; ni < 4; ni++)
                bfr[ni] = *(const bf16x8*)(Bs + (nw + ni * 16 + lrow) * 64 + ks * 32 + quad * 8);
#pragma unroll
            for (int mi = 0; mi < 4; mi++)
#pragma unroll
                for (int ni = 0; ni < 4; ni++)
                    acc[mi][ni] = __builtin_amdgcn_mfma_f32_16x16x32_bf16(af[mi], bfr[ni], acc[mi][ni], 0, 0, 0);
        }
    }

    // epilogue: C/D layout col=lane&15, row=quad*4+reg  [verified m89]
#pragma unroll
    for (int mi = 0; mi < 4; mi++) {
        int mbase = bm0 + mw + mi * 16 + quad * 4;
        int b = mbase >> 11, n = mbase & 2047;   // r never crosses batch boundary (mbase%4==0)
#pragma unroll
        for (int ni = 0; ni < 4; ni++) {
            int o = bn0 + nw + ni * 16 + lrow;
            int s  = o >> 9;
            int h  = (o >> 6) & 7;
            int dh = o & 63;
            int bh = b * 8 + h;
            if (s == 2) {
                bf16x4 pv;
#pragma unroll
                for (int r = 0; r < 4; r++) pv[r] = (bf16_t)acc[mi][ni][r];
                *(bf16x4*)(Vt + ((size_t)bh * 64 + dh) * 2048 + n) = pv;   // 8B packed
            } else if (s == 0) {
#pragma unroll
                for (int r = 0; r < 4; r++)
                    Q[((size_t)bh * 2048 + n + r) * 64 + dh] = (bf16_t)(acc[mi][ni][r] * QSCALE);
            } else {
#pragma unroll
                for (int r = 0; r < 4; r++)
                    K[((size_t)bh * 2048 + n + r) * 64 + dh] = (bf16_t)acc[mi][ni][r];
            }
        }
    }
}

// -------------------- flash attention --------------------
// Double-buffered async K/V staging via global_load_lds with XOR-chunk swizzle:
// LDS[row][cc] = G[row][cc ^ (row&7)] (16B chunks). Unpadded 64x64 tiles satisfy
// the wave-uniform-base constraint; swizzle breaks the pow-2 read conflict.
// P tile: same swizzle at pitch 64 -> write 2-way (free), read at bank minimum.
// One barrier per k-tile; loads for tile t+1 fly across tile t's compute.

__device__ __forceinline__ void stage_tile(const bf16_t* __restrict__ kb,
                                           const bf16_t* __restrict__ vb,
                                           int kt, bf16_t* ksbuf, bf16_t* vsbuf,
                                           int wave, int lane) {
#pragma unroll
    for (int part = 0; part < 2; ++part) {
        int ch  = part * 256 + wave * 64 + lane;   // chunk id 0..511
        int row = ch >> 3, cc = ch & 7;
        int scc = cc ^ (row & 7);                  // swizzled source chunk
        bf16_t* ldst = ksbuf + (size_t)(part * 256 + wave * 64) * 8;  // wave-uniform
        gl2lds16(kb + ((size_t)(kt * 64 + row)) * 64 + scc * 8, ldst);
        bf16_t* ldst2 = vsbuf + (size_t)(part * 256 + wave * 64) * 8;
        gl2lds16(vb + (size_t)row * 2048 + kt * 64 + scc * 8, ldst2);
    }
}

__global__ __launch_bounds__(256) void flash_attn(const bf16_t* __restrict__ Q,   // [32][2048][64], pre-scaled by 0.125*log2e
                                                  const bf16_t* __restrict__ K,   // [32][2048][64]
                                                  const bf16_t* __restrict__ Vt,  // [32][64][2048]
                                                  float* __restrict__ Out)        // [4][2048][512]
{
    __shared__ bf16_t Ks[2][64 * 64];
    __shared__ bf16_t Vs[2][64 * 64];
    __shared__ bf16_t Ps[4][16 * 64];
    // total 40960 B -> 4 blocks/CU exactly

    const int tid  = threadIdx.x;
    const int wave = tid >> 6;
    const int lane = tid & 63;
    const int quad = lane >> 4;
    const int c    = lane & 15;
    const int t7   = c & 7;
    const int qt = blockIdx.x;
    const int bh = blockIdx.y;
    const int b = bh >> 3, h = bh & 7;

    // Q fragments (A-operand: m=lane&15, k=quad*8+j), shifted-query source row
    int qg  = qt * 64 + wave * 16 + c;
    int src = (qg == 0) ? 0 : qg - 1;
    const bf16_t* qbase = Q + ((size_t)bh * 2048 + src) * 64;
    bf16x8 qf0 = *(const bf16x8*)(qbase + quad * 8);
    bf16x8 qf1 = *(const bf16x8*)(qbase + 32 + quad * 8);

    floatx4 o[4];
#pragma unroll
    for (int i = 0; i < 4; i++) o[i] = (floatx4)0.0f;
    float lacc[4] = {0.f, 0.f, 0.f, 0.f};

    const bf16_t* kb = K + ((size_t)bh * 2048) * 64;
    const bf16_t* vb = Vt + ((size_t)bh * 64) * 2048;
    bf16_t* pw = Ps[wave];

    stage_tile(kb, vb, 0, Ks[0], Vs[0], wave, lane);

#pragma unroll 1
    for (int kt = 0; kt < 32; ++kt) {
        const int buf = kt & 1;
        __syncthreads();   // drains vmcnt: tile kt ready; all waves done reading buf^1
        if (kt < 31)
            stage_tile(kb, vb, kt + 1, Ks[buf ^ 1], Vs[buf ^ 1], wave, lane);

        const bf16_t* ks = Ks[buf];
        const bf16_t* vs = Vs[buf];

        // S = Qc * K^T  (per wave: 16 q x 64 keys); log2e pre-folded
        floatx4 s[4];
#pragma unroll
        for (int sub = 0; sub < 4; ++sub) {
            const bf16_t* krow = ks + (sub * 16 + c) * 64;
            bf16x8 kf0 = *(const bf16x8*)(krow + ((quad ^ t7) << 3));
            bf16x8 kf1 = *(const bf16x8*)(krow + (((4 + quad) ^ t7) << 3));
            floatx4 t = (floatx4)0.0f;
            t = __builtin_amdgcn_mfma_f32_16x16x32_bf16(qf0, kf0, t, 0, 0, 0);
            t = __builtin_amdgcn_mfma_f32_16x16x32_bf16(qf1, kf1, t, 0, 0, 0);
            s[sub] = t;
        }

        // P = exp2(S); in-lane partial row sums; swizzled P write (2-way, free)
#pragma unroll
        for (int sub = 0; sub < 4; ++sub)
#pragma unroll
            for (int r = 0; r < 4; r++) {
                float p = __builtin_amdgcn_exp2f(s[sub][r]);
                lacc[r] += p;
                int row  = quad * 4 + r;
                int col8 = sub * 2 + (c >> 3);
                pw[row * 64 + ((col8 ^ (row & 7)) << 3) + t7] = (bf16_t)p;
            }
        // NO barrier: Ps is per-wave; in-wave DS ordering (lgkmcnt) suffices

        // O += P * V
#pragma unroll
        for (int ki = 0; ki < 2; ++ki) {
            bf16x8 pf = *(const bf16x8*)(pw + c * 64 + (((ki * 4 + quad) ^ t7) << 3));
#pragma unroll
            for (int sub = 0; sub < 4; ++sub) {
                const bf16_t* vrow = vs + (sub * 16 + c) * 64;
                bf16x8 vf = *(const bf16x8*)(vrow + (((ki * 4 + quad) ^ t7) << 3));
                o[sub] = __builtin_amdgcn_mfma_f32_16x16x32_bf16(pf, vf, o[sub], 0, 0, 0);
            }
        }
    }

    // final cross-lane row-sum reduction (16-lane groups)
#pragma unroll
    for (int r = 0; r < 4; r++)
#pragma unroll
        for (int d = 1; d < 16; d <<= 1)
            lacc[r] += __shfl_xor(lacc[r], d, 64);

    // epilogue: out[b][n][h*64 + d] = o / l
    int n0 = qt * 64 + wave * 16 + quad * 4;
    float* ob = Out + (size_t)b * 2048 * 512 + (size_t)h * 64;
#pragma unroll
    for (int r = 0; r < 4; r++) {
        float inv = 1.0f / lacc[r];
        float* orow = ob + (size_t)(n0 + r) * 512;
#pragma unroll
        for (int sub = 0; sub < 4; ++sub)
            orow[sub * 16 + c] = o[sub][r] * inv;
    }
}

// -------------------- launch --------------------
extern "C" void kernel_launch(void* const* d_in, const int* in_sizes, int n_in,
                              void* d_out, int out_size, void* d_ws, size_t ws_size,
                              hipStream_t stream) {
    const float* x = (const float*)d_in[0];   // [4,2048,512]
    const float* w = (const float*)d_in[1];   // [1536,512]
    float* out = (float*)d_out;               // [4,2048,512]

    char* ws = (char*)d_ws;
    bf16_t* xb = (bf16_t*)(ws);                       //  8 MB
    bf16_t* wb = (bf16_t*)(ws + 8388608);             //  1.5 MB
    bf16_t* q  = (bf16_t*)(ws + 9961472);             //  8 MB
    bf16_t* k  = (bf16_t*)(ws + 18350080);            //  8 MB
    bf16_t* vt = (bf16_t*)(ws + 26738688);            //  8 MB (end 33.5 MB)

    convert_kernel<<<4864, 256, 0, stream>>>(x, xb, w, wb, 1048576);
    qkv_gemm<<<dim3(64, 12), 256, 0, stream>>>(xb, wb, q, k, vt);
    flash_attn<<<dim3(32, 32), 256, 0, stream>>>(q, k, vt, out);
}

// Round 5
// 154.394 us; speedup vs baseline: 1.6105x; 1.0382x over previous
//
#include <hip/hip_runtime.h>
#include <hip/hip_bf16.h>
#include <stdint.h>

typedef __bf16 bf16_t;
typedef float floatx4 __attribute__((ext_vector_type(4)));
typedef __bf16 bf16x8 __attribute__((ext_vector_type(8)));
typedef __bf16 bf16x4 __attribute__((ext_vector_type(4)));

// scale = DH^-0.5 * log2(e), folded into Q at GEMM epilogue so softmax uses raw exp2
#define QSCALE 0.1803368801111204f

// -------------------- async global->LDS (16B) --------------------
__device__ __forceinline__ void gl2lds16(const bf16_t* g, bf16_t* l) {
    __builtin_amdgcn_global_load_lds(
        (const __attribute__((address_space(1))) unsigned int*)g,
        (__attribute__((address_space(3))) unsigned int*)l,
        16, 0, 0);
}

// -------------------- fp32 -> bf16 convert (x and W fused) --------------------
__global__ __launch_bounds__(256) void convert_kernel(const float* __restrict__ x,
                                                      bf16_t* __restrict__ xb,
                                                      const float* __restrict__ w,
                                                      bf16_t* __restrict__ wb,
                                                      int nx4) {   // x chunks; W chunks follow
    int i = blockIdx.x * 256 + threadIdx.x;
    const float* in; bf16_t* out; int j;
    if (i < nx4) { in = x; out = xb; j = i; }
    else         { in = w; out = wb; j = i - nx4; }
    float4 v = ((const float4*)in)[j];
    bf16x4 o;
    o.x = (bf16_t)v.x; o.y = (bf16_t)v.y; o.z = (bf16_t)v.z; o.w = (bf16_t)v.w;
    ((bf16x4*)out)[j] = o;
}

// -------------------- QKV projection GEMM (gemm_bt) --------------------
// R5: XOR-chunk swizzle on LDS staging (R4-proven in flash_attn, 9.4M->0 conflicts).
// Old layout: row stride 32 dwords => each quad's b128 frag read put 16 lanes on a
// 4-bank group (16-way, the m98 1.7e7-conflict pattern). Swizzled chunks cover all
// 32 banks at 2 lanes/bank (free, m136).
__global__ __launch_bounds__(256) void qkv_gemm(const bf16_t* __restrict__ X,   // [8192][512]
                                                const bf16_t* __restrict__ W,   // [1536][512]
                                                bf16_t* __restrict__ Q,         // [32][2048][64] (pre-scaled)
                                                bf16_t* __restrict__ K,         // [32][2048][64]
                                                bf16_t* __restrict__ Vt)        // [32][64][2048]
{
    __shared__ bf16_t As[128 * 64];
    __shared__ bf16_t Bs[128 * 64];

    const int tid  = threadIdx.x;
    const int wave = tid >> 6;
    const int lane = tid & 63;
    const int quad = lane >> 4;
    const int lrow = lane & 15;
    const int t7g  = lrow & 7;      // = row&7 of every fragment row this lane touches
    const int bm0 = blockIdx.x * 128;
    const int bn0 = blockIdx.y * 128;
    const int mw = (wave >> 1) * 64;
    const int nw = (wave & 1) * 64;
    const int wbase = tid & 192;   // wave*64, wave-uniform

    floatx4 acc[4][4];
#pragma unroll
    for (int i = 0; i < 4; i++)
#pragma unroll
        for (int j = 0; j < 4; j++) acc[i][j] = (floatx4)0.0f;

#pragma unroll 1
    for (int kb = 0; kb < 8; ++kb) {
        const int k0 = kb * 64;
        __syncthreads();
#pragma unroll
        for (int r = 0; r < 4; ++r) {
            int c = r * 256 + tid;
            int row = c >> 3, kc = c & 7;
            int skc = kc ^ (row & 7);   // swizzled source chunk
            gl2lds16(X + (size_t)(bm0 + row) * 512 + k0 + skc * 8,
                     As + (size_t)(r * 256 + wbase) * 8);
        }
#pragma unroll
        for (int r = 0; r < 4; ++r) {
            int c = r * 256 + tid;
            int row = c >> 3, kc = c & 7;
            int skc = kc ^ (row & 7);
            gl2lds16(W + (size_t)(bn0 + row) * 512 + k0 + skc * 8,
                     Bs + (size_t)(r * 256 + wbase) * 8);
        }
        __syncthreads();
#pragma unroll
        for (int ks = 0; ks < 2; ++ks) {
            bf16x8 af[4], bfr[4];
#pragma unroll
            for (int mi = 0; mi < 4; mi++)
                af[mi] = *(const bf16x8*)(As + (mw + mi * 16 + lrow) * 64 + (((ks * 4 + quad) ^ t7g) << 3));
#pragma unroll
            for (int ni = 0; ni < 4; ni++)
                bfr[ni] = *(const bf16x8*)(Bs + (nw + ni * 16 + lrow) * 64 + (((ks * 4 + quad) ^ t7g) << 3));
#pragma unroll
            for (int mi = 0; mi < 4; mi++)
#pragma unroll
                for (int ni = 0; ni < 4; ni++)
                    acc[mi][ni] = __builtin_amdgcn_mfma_f32_16x16x32_bf16(af[mi], bfr[ni], acc[mi][ni], 0, 0, 0);
        }
    }

    // epilogue: C/D layout col=lane&15, row=quad*4+reg  [verified m89]
#pragma unroll
    for (int mi = 0; mi < 4; mi++) {
        int mbase = bm0 + mw + mi * 16 + quad * 4;
        int b = mbase >> 11, n = mbase & 2047;   // r never crosses batch boundary (mbase%4==0)
#pragma unroll
        for (int ni = 0; ni < 4; ni++) {
            int o = bn0 + nw + ni * 16 + lrow;
            int s  = o >> 9;
            int h  = (o >> 6) & 7;
            int dh = o & 63;
            int bh = b * 8 + h;
            if (s == 2) {
                bf16x4 pv;
#pragma unroll
                for (int r = 0; r < 4; r++) pv[r] = (bf16_t)acc[mi][ni][r];
                *(bf16x4*)(Vt + ((size_t)bh * 64 + dh) * 2048 + n) = pv;   // 8B packed
            } else if (s == 0) {
#pragma unroll
                for (int r = 0; r < 4; r++)
                    Q[((size_t)bh * 2048 + n + r) * 64 + dh] = (bf16_t)(acc[mi][ni][r] * QSCALE);
            } else {
#pragma unroll
                for (int r = 0; r < 4; r++)
                    K[((size_t)bh * 2048 + n + r) * 64 + dh] = (bf16_t)acc[mi][ni][r];
            }
        }
    }
}

// -------------------- flash attention (unchanged from R4) --------------------
__device__ __forceinline__ void stage_tile(const bf16_t* __restrict__ kb,
                                           const bf16_t* __restrict__ vb,
                                           int kt, bf16_t* ksbuf, bf16_t* vsbuf,
                                           int wave, int lane) {
#pragma unroll
    for (int part = 0; part < 2; ++part) {
        int ch  = part * 256 + wave * 64 + lane;   // chunk id 0..511
        int row = ch >> 3, cc = ch & 7;
        int scc = cc ^ (row & 7);                  // swizzled source chunk
        bf16_t* ldst = ksbuf + (size_t)(part * 256 + wave * 64) * 8;  // wave-uniform
        gl2lds16(kb + ((size_t)(kt * 64 + row)) * 64 + scc * 8, ldst);
        bf16_t* ldst2 = vsbuf + (size_t)(part * 256 + wave * 64) * 8;
        gl2lds16(vb + (size_t)row * 2048 + kt * 64 + scc * 8, ldst2);
    }
}

__global__ __launch_bounds__(256) void flash_attn(const bf16_t* __restrict__ Q,   // [32][2048][64], pre-scaled by 0.125*log2e
                                                  const bf16_t* __restrict__ K,   // [32][2048][64]
                                                  const bf16_t* __restrict__ Vt,  // [32][64][2048]
                                                  float* __restrict__ Out)        // [4][2048][512]
{
    __shared__ bf16_t Ks[2][64 * 64];
    __shared__ bf16_t Vs[2][64 * 64];
    __shared__ bf16_t Ps[4][16 * 64];
    // total 40960 B -> 4 blocks/CU

    const int tid  = threadIdx.x;
    const int wave = tid >> 6;
    const int lane = tid & 63;
    const int quad = lane >> 4;
    const int c    = lane & 15;
    const int t7   = c & 7;
    const int qt = blockIdx.x;
    const int bh = blockIdx.y;
    const int b = bh >> 3, h = bh & 7;

    // Q fragments (A-operand: m=lane&15, k=quad*8+j), shifted-query source row
    int qg  = qt * 64 + wave * 16 + c;
    int src = (qg == 0) ? 0 : qg - 1;
    const bf16_t* qbase = Q + ((size_t)bh * 2048 + src) * 64;
    bf16x8 qf0 = *(const bf16x8*)(qbase + quad * 8);
    bf16x8 qf1 = *(const bf16x8*)(qbase + 32 + quad * 8);

    floatx4 o[4];
#pragma unroll
    for (int i = 0; i < 4; i++) o[i] = (floatx4)0.0f;
    float lacc[4] = {0.f, 0.f, 0.f, 0.f};

    const bf16_t* kb = K + ((size_t)bh * 2048) * 64;
    const bf16_t* vb = Vt + ((size_t)bh * 64) * 2048;
    bf16_t* pw = Ps[wave];

    stage_tile(kb, vb, 0, Ks[0], Vs[0], wave, lane);

#pragma unroll 1
    for (int kt = 0; kt < 32; ++kt) {
        const int buf = kt & 1;
        __syncthreads();   // drains vmcnt: tile kt ready; all waves done reading buf^1
        if (kt < 31)
            stage_tile(kb, vb, kt + 1, Ks[buf ^ 1], Vs[buf ^ 1], wave, lane);

        const bf16_t* ks = Ks[buf];
        const bf16_t* vs = Vs[buf];

        // S = Qc * K^T  (per wave: 16 q x 64 keys); log2e pre-folded
        floatx4 s[4];
#pragma unroll
        for (int sub = 0; sub < 4; ++sub) {
            const bf16_t* krow = ks + (sub * 16 + c) * 64;
            bf16x8 kf0 = *(const bf16x8*)(krow + ((quad ^ t7) << 3));
            bf16x8 kf1 = *(const bf16x8*)(krow + (((4 + quad) ^ t7) << 3));
            floatx4 t = (floatx4)0.0f;
            t = __builtin_amdgcn_mfma_f32_16x16x32_bf16(qf0, kf0, t, 0, 0, 0);
            t = __builtin_amdgcn_mfma_f32_16x16x32_bf16(qf1, kf1, t, 0, 0, 0);
            s[sub] = t;
        }

        // P = exp2(S); in-lane partial row sums; swizzled P write (2-way, free)
#pragma unroll
        for (int sub = 0; sub < 4; ++sub)
#pragma unroll
            for (int r = 0; r < 4; r++) {
                float p = __builtin_amdgcn_exp2f(s[sub][r]);
                lacc[r] += p;
                int row  = quad * 4 + r;
                int col8 = sub * 2 + (c >> 3);
                pw[row * 64 + ((col8 ^ (row & 7)) << 3) + t7] = (bf16_t)p;
            }
        // NO barrier: Ps is per-wave; in-wave DS ordering (lgkmcnt) suffices

        // O += P * V
#pragma unroll
        for (int ki = 0; ki < 2; ++ki) {
            bf16x8 pf = *(const bf16x8*)(pw + c * 64 + (((ki * 4 + quad) ^ t7) << 3));
#pragma unroll
            for (int sub = 0; sub < 4; ++sub) {
                const bf16_t* vrow = vs + (sub * 16 + c) * 64;
                bf16x8 vf = *(const bf16x8*)(vrow + (((ki * 4 + quad) ^ t7) << 3));
                o[sub] = __builtin_amdgcn_mfma_f32_16x16x32_bf16(pf, vf, o[sub], 0, 0, 0);
            }
        }
    }

    // final cross-lane row-sum reduction (16-lane groups)
#pragma unroll
    for (int r = 0; r < 4; r++)
#pragma unroll
        for (int d = 1; d < 16; d <<= 1)
            lacc[r] += __shfl_xor(lacc[r], d, 64);

    // epilogue: out[b][n][h*64 + d] = o / l
    int n0 = qt * 64 + wave * 16 + quad * 4;
    float* ob = Out + (size_t)b * 2048 * 512 + (size_t)h * 64;
#pragma unroll
    for (int r = 0; r < 4; r++) {
        float inv = 1.0f / lacc[r];
        float* orow = ob + (size_t)(n0 + r) * 512;
#pragma unroll
        for (int sub = 0; sub < 4; ++sub)
            orow[sub * 16 + c] = o[sub][r] * inv;
    }
}

// -------------------- launch --------------------
extern "C" void kernel_launch(void* const* d_in, const int* in_sizes, int n_in,
                              void* d_out, int out_size, void* d_ws, size_t ws_size,
                              hipStream_t stream) {
    const float* x = (const float*)d_in[0];   // [4,2048,512]
    const float* w = (const float*)d_in[1];   // [1536,512]
    float* out = (float*)d_out;               // [4,2048,512]

    char* ws = (char*)d_ws;
    bf16_t* xb = (bf16_t*)(ws);                       //  8 MB
    bf16_t* wb = (bf16_t*)(ws + 8388608);             //  1.5 MB
    bf16_t* q  = (bf16_t*)(ws + 9961472);             //  8 MB
    bf16_t* k  = (bf16_t*)(ws + 18350080);            //  8 MB
    bf16_t* vt = (bf16_t*)(ws + 26738688);            //  8 MB (end 33.5 MB)

    convert_kernel<<<4864, 256, 0, stream>>>(x, xb, w, wb, 1048576);
    qkv_gemm<<<dim3(64, 12), 256, 0, stream>>>(xb, wb, q, k, vt);
    flash_attn<<<dim3(32, 32), 256, 0, stream>>>(q, k, vt, out);
}